// Round 3
// baseline (144.876 us; speedup 1.0000x reference)
//
#include <hip/hip_runtime.h>

#define B_DIM   1024
#define IN_DIM  1024
#define OUT_DIM 2048
#define NBITS   6
#define NENT    64   // 1 << NBITS

#define OB   256     // o per block (== blockDim.x)
#define BB   8       // b per block -> x tile 32 KB

// R3: occupancy restructure. Evidence: R1's two-half fold (different register
// structure) timed IDENTICAL to baseline (69.64 vs 69.76) -> inner loop is not
// the critical path. The 41us/256MB fills at 82% HBM in the profile + lut_fused
// absent from top-5 (<40.4us) say ~41us of dur_us is harness ws-poison; the
// kernel itself is ~28.6us vs a ~10us latency-hidden floor. Old kernel: 65KB
// LDS -> 2 blocks/CU -> 2 waves/SIMD -> latency-exposed serial phases.
// This version: no lut LDS staging (direct global row load, L2/L3-resident
// 0.5MB table), BB=8 -> 32KB x tile, launch_bounds(256,4) -> VGPR<=128 ->
// 4 blocks/CU = 16 waves/CU (2x), grid 1024 blocks, ONE barrier total.
__global__ __launch_bounds__(256, 4) void lut_fused(
    const float* __restrict__ x,
    const float* __restrict__ lut,
    const int*   __restrict__ mapping,
    float*       __restrict__ out)
{
    __shared__ __align__(16) float smem[BB * IN_DIM];   // 32 KB x tile
    const int tid = threadIdx.x;
    const int o   = blockIdx.x * OB + tid;
    const int b0  = blockIdx.y * BB;

    // ---- own lut row, direct from global (16 x float4, 256B/lane stride;
    //      table is 0.5MB total and re-read 128x -> L2/L3 resident) ----
    float v[NENT];
    const float4* lsrc = (const float4*)(lut + (size_t)o * NENT);
#pragma unroll
    for (int k = 0; k < NENT / 4; k++) {
        const float4 t = lsrc[k];
        v[4 * k + 0] = t.x; v[4 * k + 1] = t.y;
        v[4 * k + 2] = t.z; v[4 * k + 3] = t.w;
    }

    // ---- stage x tile (coalesced float4, linear LDS) ----
    const float4* xsrc = (const float4*)(x + (size_t)b0 * IN_DIM);
    float4* xdst = (float4*)smem;
#pragma unroll
    for (int i = 0; i < (BB * IN_DIM / 4) / OB; i++) {  // 8 iters
        xdst[i * OB + tid] = xsrc[i * OB + tid];
    }

    // mapping for my o (reused across all b of this block)
    int mp[NBITS];
#pragma unroll
    for (int j = 0; j < NBITS; j++) mp[j] = mapping[(size_t)o * NBITS + j];

    // ---- in-register finite-difference transform: per bit j, hi -= lo ----
#pragma unroll
    for (int j = 0; j < NBITS; j++) {
#pragma unroll
        for (int k = 0; k < NENT; k++) {
            if ((k >> j) & 1) v[k] -= v[k ^ (1 << j)];
        }
    }

    __syncthreads();   // x tile visible; lut/transform path is thread-private

    // ---- main loop: 6 LDS gathers + 63-FMA two-half Horner fold per output.
    //      bi*IN_DIM*4 <= 28KB folds into ds_read offset immediates. ----
#pragma unroll 2
    for (int bi = 0; bi < BB; bi++) {
        float xv[NBITS];
#pragma unroll
        for (int j = 0; j < NBITS; j++) xv[j] = smem[bi * IN_DIM + mp[j]];

        float s0, s1;
        {
            float u[16];
#pragma unroll
            for (int m = 0; m < 16; m++)
                u[m] = fmaf(xv[0], v[2 * m + 1], v[2 * m]);
#pragma unroll
            for (int j = 1; j < 5; j++) {
#pragma unroll
                for (int m = 0; m < (16 >> j); m++)
                    u[m] = fmaf(xv[j], u[2 * m + 1], u[2 * m]);
            }
            s0 = u[0];
        }
        {
            float u[16];
#pragma unroll
            for (int m = 0; m < 16; m++)
                u[m] = fmaf(xv[0], v[32 + 2 * m + 1], v[32 + 2 * m]);
#pragma unroll
            for (int j = 1; j < 5; j++) {
#pragma unroll
                for (int m = 0; m < (16 >> j); m++)
                    u[m] = fmaf(xv[j], u[2 * m + 1], u[2 * m]);
            }
            s1 = u[0];
        }
        out[(size_t)(b0 + bi) * OUT_DIM + o] = fmaf(xv[5], s1, s0);
    }
}

extern "C" void kernel_launch(void* const* d_in, const int* in_sizes, int n_in,
                              void* d_out, int out_size, void* d_ws, size_t ws_size,
                              hipStream_t stream) {
    const float* x       = (const float*)d_in[0];
    const float* lut     = (const float*)d_in[1];
    const int*   mapping = (const int*)d_in[2];
    float*       out     = (float*)d_out;
    (void)d_ws; (void)ws_size;

    const dim3 grid(OUT_DIM / OB, B_DIM / BB);   // 8 x 128 = 1024 blocks, 4/CU
    lut_fused<<<grid, 256, 0, stream>>>(x, lut, mapping, out);
}

// Round 4
// 72.597 us; speedup vs baseline: 1.9956x; 1.9956x over previous
//
#include <hip/hip_runtime.h>

#define B_DIM   1024
#define IN_DIM  1024
#define OUT_DIM 2048
#define NBITS   6
#define NENT    64   // 1 << NBITS

#define OB   256     // o per block (== blockDim.x)
#define BB   8       // b per block -> x tile 32 KB

// R4: un-spill R3. R3's counters: VGPR_Count=64, FETCH+WRITE ~320MB/dispatch
// (vs ~13MB compulsory), VALUBusy 3.8% -> launch_bounds(256,4) forced the
// allocator into a tiny file and v[64]+u[16] spilled to scratch; kernel became
// a 92us scratch-BW benchmark. Fix: (a) launch_bounds(256,2) so the allocator
// never force-spills; (b) reduce NATURAL peak pressure under the 128-VGPR
// occupancy cliff (m69: waves step at 64/128/256) via four quarter-folds
// (bits 0-3 in 16-coeff quarters, peak 8 temps) + 3 combining FMAs for bits
// 4-5. Peak live ~= v[64] + 2x(8+4+6) + addr ~= 110 at unroll 2 -> expect
// 4 waves/SIMD organically. Keep R3's good bits: BB=8, direct global lut row
// (L2/L3-resident), single barrier, 32KB LDS.
__global__ __launch_bounds__(256, 2) void lut_fused(
    const float* __restrict__ x,
    const float* __restrict__ lut,
    const int*   __restrict__ mapping,
    float*       __restrict__ out)
{
    __shared__ __align__(16) float smem[BB * IN_DIM];   // 32 KB x tile
    const int tid = threadIdx.x;
    const int o   = blockIdx.x * OB + tid;
    const int b0  = blockIdx.y * BB;

    // ---- own lut row, direct from global (16 x float4; 0.5MB table is
    //      L2/L3-resident across its 128 re-reads) ----
    float v[NENT];
    const float4* lsrc = (const float4*)(lut + (size_t)o * NENT);
#pragma unroll
    for (int k = 0; k < NENT / 4; k++) {
        const float4 t = lsrc[k];
        v[4 * k + 0] = t.x; v[4 * k + 1] = t.y;
        v[4 * k + 2] = t.z; v[4 * k + 3] = t.w;
    }

    // ---- stage x tile (coalesced float4, linear LDS) ----
    const float4* xsrc = (const float4*)(x + (size_t)b0 * IN_DIM);
    float4* xdst = (float4*)smem;
#pragma unroll
    for (int i = 0; i < (BB * IN_DIM / 4) / OB; i++) {  // 8 iters
        xdst[i * OB + tid] = xsrc[i * OB + tid];
    }

    // mapping for my o (reused across all b of this block)
    int mp[NBITS];
#pragma unroll
    for (int j = 0; j < NBITS; j++) mp[j] = mapping[(size_t)o * NBITS + j];

    // ---- in-register finite-difference transform: per bit j, hi -= lo ----
#pragma unroll
    for (int j = 0; j < NBITS; j++) {
#pragma unroll
        for (int k = 0; k < NENT; k++) {
            if ((k >> j) & 1) v[k] -= v[k ^ (1 << j)];
        }
    }

    __syncthreads();   // x tile visible; lut path is thread-private

    // ---- main loop: 6 LDS gathers + 66-FMA quarter-fold per output.
    //      mp[j]*4 is a loop-invariant address reg; bi*IN_DIM*4 <= 28672
    //      folds into the ds_read offset immediate. ----
#pragma unroll 2
    for (int bi = 0; bi < BB; bi++) {
        float xv[NBITS];
#pragma unroll
        for (int j = 0; j < NBITS; j++) xv[j] = smem[bi * IN_DIM + mp[j]];

        float q[4];
#pragma unroll
        for (int qi = 0; qi < 4; qi++) {
            float u[8];
#pragma unroll
            for (int m = 0; m < 8; m++)
                u[m] = fmaf(xv[0], v[16 * qi + 2 * m + 1], v[16 * qi + 2 * m]);
#pragma unroll
            for (int j = 1; j < 4; j++) {
#pragma unroll
                for (int m = 0; m < (8 >> j); m++)
                    u[m] = fmaf(xv[j], u[2 * m + 1], u[2 * m]);
            }
            q[qi] = u[0];
        }
        const float s0 = fmaf(xv[4], q[1], q[0]);
        const float s1 = fmaf(xv[4], q[3], q[2]);
        out[(size_t)(b0 + bi) * OUT_DIM + o] = fmaf(xv[5], s1, s0);
    }
}

extern "C" void kernel_launch(void* const* d_in, const int* in_sizes, int n_in,
                              void* d_out, int out_size, void* d_ws, size_t ws_size,
                              hipStream_t stream) {
    const float* x       = (const float*)d_in[0];
    const float* lut     = (const float*)d_in[1];
    const int*   mapping = (const int*)d_in[2];
    float*       out     = (float*)d_out;
    (void)d_ws; (void)ws_size;

    const dim3 grid(OUT_DIM / OB, B_DIM / BB);   // 8 x 128 = 1024 blocks
    lut_fused<<<grid, 256, 0, stream>>>(x, lut, mapping, out);
}

// Round 5
// 68.211 us; speedup vs baseline: 2.1239x; 1.0643x over previous
//
#include <hip/hip_runtime.h>

#define B_DIM   1024
#define IN_DIM  1024
#define OUT_DIM 2048
#define NBITS   6
#define NENT    64   // 1 << NBITS

#define OB   256     // o per block (== blockDim.x)
#define BB   16      // b per block -> x tile 64 KB
#define NXCD 8

// R5: XCD-locality restructure. Evidence: three structurally different
// register-resident kernels (R0: 65KB-LDS/3-barrier, R2: two-half fold,
// R4: BB=8/direct-lut/1-barrier) all plateau at 28-31us kernel time ->
// inner structure/occupancy are not the lever. R4 (more cross-block re-read
// traffic) was WORSE than R0 -> locality is. Default (8,64) grid linearizes
// x-fastest -> XCD = ox -> the 8 blocks sharing an x-tile land on 8 DIFFERENT
// XCDs (non-coherent L2s) -> every x-tile fetched 8x from L3/HBM, and the
// bench's 256MB ws-poison sweeps L3 every iteration so nothing stays warm.
// Fix: 1D grid, chunked bijective swizzle (xcd = bid&7 owns by-chunk
// [xcd*8, xcd*8+8) with all 8 ox back-to-back) -> each XCD pulls its 8
// x-tiles (512KB) + full lut (512KB) into its 4MB L2 ONCE; HBM ~= compulsory.
// Keep: BB=16, direct-reg lut row, quarter-fold (peak 8 temps), 1 barrier,
// launch_bounds(256,2) (LDS caps residency at 2 blocks/CU regardless).
__global__ __launch_bounds__(256, 2) void lut_fused(
    const float* __restrict__ x,
    const float* __restrict__ lut,
    const int*   __restrict__ mapping,
    float*       __restrict__ out)
{
    __shared__ __align__(16) float smem[BB * IN_DIM];   // 64 KB x tile
    const int tid = threadIdx.x;

    // ---- XCD-chunked bijective swizzle (nwg=512, nwg%8==0) ----
    const int bid = blockIdx.x;
    const int xcd = bid & (NXCD - 1);          // hw round-robin: bid%8 = XCD
    const int lin = xcd * (512 / NXCD) + (bid >> 3);
    const int ox  = lin & 7;                   // o-group cycles fastest in-XCD
    const int by  = lin >> 3;                  // by in [xcd*8, xcd*8+8)

    const int o   = ox * OB + tid;
    const int b0  = by * BB;

    // ---- own lut row, direct from global (16 x float4; per-XCD L2-resident
    //      after first touch under the swizzle) ----
    float v[NENT];
    const float4* lsrc = (const float4*)(lut + (size_t)o * NENT);
#pragma unroll
    for (int k = 0; k < NENT / 4; k++) {
        const float4 t = lsrc[k];
        v[4 * k + 0] = t.x; v[4 * k + 1] = t.y;
        v[4 * k + 2] = t.z; v[4 * k + 3] = t.w;
    }

    // ---- stage x tile (coalesced float4, linear LDS) ----
    const float4* xsrc = (const float4*)(x + (size_t)b0 * IN_DIM);
    float4* xdst = (float4*)smem;
#pragma unroll
    for (int i = 0; i < (BB * IN_DIM / 4) / OB; i++) {  // 16 iters
        xdst[i * OB + tid] = xsrc[i * OB + tid];
    }

    // mapping for my o (reused across all b of this block)
    int mp[NBITS];
#pragma unroll
    for (int j = 0; j < NBITS; j++) mp[j] = mapping[(size_t)o * NBITS + j];

    // ---- in-register finite-difference transform (independent of x tile;
    //      compiler overlaps it with the staging latency) ----
#pragma unroll
    for (int j = 0; j < NBITS; j++) {
#pragma unroll
        for (int k = 0; k < NENT; k++) {
            if ((k >> j) & 1) v[k] -= v[k ^ (1 << j)];
        }
    }

    __syncthreads();   // x tile visible

    // ---- main loop: 6 LDS gathers + 66-FMA quarter-fold per output ----
#pragma unroll 2
    for (int bi = 0; bi < BB; bi++) {
        float xv[NBITS];
#pragma unroll
        for (int j = 0; j < NBITS; j++) xv[j] = smem[bi * IN_DIM + mp[j]];

        float q[4];
#pragma unroll
        for (int qi = 0; qi < 4; qi++) {
            float u[8];
#pragma unroll
            for (int m = 0; m < 8; m++)
                u[m] = fmaf(xv[0], v[16 * qi + 2 * m + 1], v[16 * qi + 2 * m]);
#pragma unroll
            for (int j = 1; j < 4; j++) {
#pragma unroll
                for (int m = 0; m < (8 >> j); m++)
                    u[m] = fmaf(xv[j], u[2 * m + 1], u[2 * m]);
            }
            q[qi] = u[0];
        }
        const float s0 = fmaf(xv[4], q[1], q[0]);
        const float s1 = fmaf(xv[4], q[3], q[2]);
        out[(size_t)(b0 + bi) * OUT_DIM + o] = fmaf(xv[5], s1, s0);
    }
}

extern "C" void kernel_launch(void* const* d_in, const int* in_sizes, int n_in,
                              void* d_out, int out_size, void* d_ws, size_t ws_size,
                              hipStream_t stream) {
    const float* x       = (const float*)d_in[0];
    const float* lut     = (const float*)d_in[1];
    const int*   mapping = (const int*)d_in[2];
    float*       out     = (float*)d_out;
    (void)d_ws; (void)ws_size;

    lut_fused<<<dim3(512), 256, 0, stream>>>(x, lut, mapping, out);
}